// Round 7
// baseline (309.343 us; speedup 1.0000x reference)
//
#include <hip/hip_runtime.h>
#include <hip/hip_bf16.h>
#include <cstdint>
#include <cstddef>

#define DM   256
#define DI   512
#define DS   16
#define LSEQ 4096
#define BATCH 2
#define BLROWS (BATCH * LSEQ)   /* 8192 */
#define NCH  256                /* chunks per sequence */
#define CLEN 16                 /* steps per chunk */
#define NSC  16                 /* superchunks per sequence (16 chunks each) */
#define XCP  520                /* padded LDS row stride (u16) */

typedef __bf16 bf16x8 __attribute__((ext_vector_type(8)));
typedef float  f32x4  __attribute__((ext_vector_type(4)));
typedef unsigned short u16;
typedef u16 u16x8 __attribute__((ext_vector_type(8)));

__device__ __forceinline__ u16 f2bfu(float f) {
    union { float f; unsigned u; } c; c.f = f;
    unsigned u = c.u;
    return (u16)((u + 0x7fffu + ((u >> 16) & 1u)) >> 16);
}
__device__ __forceinline__ float bfu2f(u16 u) {
    union { unsigned u; float f; } c; c.u = ((unsigned)u) << 16; return c.f;
}
__device__ __forceinline__ float siluf(float v) {
    return v * (1.0f / (1.0f + __expf(-v)));
}

/* squaring-tree powers: an[n] = e1^(n+1), dep-depth 4 (R5/R6-verified) */
#define POW_TREE(an, e1)                                                     \
    {   float e2 = (e1)*(e1), e4 = e2*e2, e8 = e4*e4;                        \
        an[0]=(e1); an[1]=e2; an[2]=e2*(e1); an[3]=e4; an[4]=e4*(e1);        \
        an[5]=e4*e2; an[6]=e4*an[2]; an[7]=e8; an[8]=e8*(e1); an[9]=e8*e2;   \
        an[10]=e8*an[2]; an[11]=e8*e4; an[12]=e8*an[4]; an[13]=e8*an[5];     \
        an[14]=e8*an[6]; an[15]=e8*e8; }

/* ---------------- merged startup casts ---------------- */
#define N_INW  (2*1024*256)
#define N_OUTW (2*256*512)
#define N_XPW  (2*64*512)
#define N_Z    (BLROWS*DM)
__global__ __launch_bounds__(256) void cast_all_k(
    const float* __restrict__ in_w, const float* __restrict__ out_w,
    const float* __restrict__ xp_w, const float* __restrict__ z,
    u16* __restrict__ inw_bf, u16* __restrict__ outw_bf,
    u16* __restrict__ xpw_bf, u16* __restrict__ z_bf) {
    int i = blockIdx.x * 256 + threadIdx.x;
    if (i < N_INW) {
        inw_bf[i] = f2bfu(in_w[i]);
    } else if (i < N_INW + N_OUTW) {
        int j = i - N_INW;
        outw_bf[j] = f2bfu(out_w[j]);
    } else if (i < N_INW + N_OUTW + N_XPW) {
        int j = i - (N_INW + N_OUTW);
        int k = j & 511, o = (j >> 9) & 63, l = j >> 15;
        xpw_bf[j] = f2bfu((o < 48) ? xp_w[(l * 48 + o) * 512 + k] : 0.0f);
    } else {
        int j = i - (N_INW + N_OUTW + N_XPW);
        z_bf[j] = f2bfu(z[j]);
    }
}

/* ---------------- fused A: in_proj MFMA -> conv+silu -> x_proj -> dt ->
   chunk scan -> P,S.  grid (NCH, BATCH) = 512 blocks, 512 threads.
   Each block computes its own 32-row in_proj tile (rows bl0-8..bl0+23,
   same 8-MFMA K-chain as a plain GEMM -> bit-identical bf16 xz).  x-half
   stays in LDS; gate half -> compact global buffer for fused_c. -------- */
__global__ __launch_bounds__(512, 4) void fused_a_k(
    const __bf16* __restrict__ Az, const __bf16* __restrict__ inw,
    const float* __restrict__ cw, const float* __restrict__ cb,
    const __bf16* __restrict__ xpw,
    const float* __restrict__ dtw, const float* __restrict__ dtb,
    const float* __restrict__ Alog,
    u16* __restrict__ gate, u16* __restrict__ xcb, u16* __restrict__ dtob,
    float* __restrict__ BCg, u16* __restrict__ Pb, u16* __restrict__ Sb) {
    __shared__ u16 smem[32 * XCP];         /* 33.3 KB union:
        phase0-1: xz x-half [32][XCP]
        phase2+ : xc [16][XCP] (bytes 0..16639) + xd f32[2][16*68] (from 16640) */
    float* xd = (float*)&smem[16 * XCP];
    int tid = threadIdx.x;
    int c = blockIdx.x, b = blockIdx.y;
    int flat = b * NCH + c;
    int bl0 = b * LSEQ + c * CLEN;
    int l0 = c * CLEN;
    int d = tid;

    /* phase 0: in_proj tile [32 x 1024] = Az[32,256] @ inw[1024,256]^T.
       8 waves: wave ng covers cols ng*128..+127 (2 passes x 4 n-tiles x 2 m). */
    {
        int wave = tid >> 6, lane = tid & 63;
        int r15 = lane & 15, q = lane >> 4;
        int ng = wave;
        int ar0 = bl0 - 8 + r15; if (ar0 < 0) ar0 = 0;
        int ar1 = bl0 + 8 + r15; if (ar1 > BLROWS - 1) ar1 = BLROWS - 1;
        const __bf16* Ap0 = Az + (size_t)ar0 * 256 + q * 8;
        const __bf16* Ap1 = Az + (size_t)ar1 * 256 + q * 8;
        #pragma unroll
        for (int pass = 0; pass < 2; ++pass) {
            int ncol = ng * 128 + pass * 64;
            f32x4 acc[2][4] = {};
            #pragma unroll
            for (int k = 0; k < 8; ++k) {
                bf16x8 a0 = *(const bf16x8*)(Ap0 + k * 32);
                bf16x8 a1 = *(const bf16x8*)(Ap1 + k * 32);
                #pragma unroll
                for (int ni = 0; ni < 4; ++ni) {
                    bf16x8 bf = *(const bf16x8*)(inw +
                        (size_t)(ncol + ni*16 + r15) * 256 + k*32 + q*8);
                    acc[0][ni] = __builtin_amdgcn_mfma_f32_16x16x32_bf16(a0, bf, acc[0][ni], 0, 0, 0);
                    acc[1][ni] = __builtin_amdgcn_mfma_f32_16x16x32_bf16(a1, bf, acc[1][ni], 0, 0, 0);
                }
            }
            if (ng < 4) {          /* x-half -> LDS rows 0..31 */
                #pragma unroll
                for (int mt = 0; mt < 2; ++mt)
                    #pragma unroll
                    for (int ni = 0; ni < 4; ++ni)
                        #pragma unroll
                        for (int r = 0; r < 4; ++r)
                            smem[(mt*16 + q*4 + r) * XCP + ncol + ni*16 + r15] =
                                f2bfu(acc[mt][ni][r]);
            } else {               /* gate -> global, chunk rows only */
                #pragma unroll
                for (int mt = 0; mt < 2; ++mt)
                    #pragma unroll
                    for (int ni = 0; ni < 4; ++ni)
                        #pragma unroll
                        for (int r = 0; r < 4; ++r) {
                            int ro = mt*16 + q*4 + r;
                            if (ro >= 8 && ro < 24)
                                gate[(size_t)(bl0 + ro - 8) * 512 +
                                     (ncol - 512) + ni*16 + r15] = f2bfu(acc[mt][ni][r]);
                        }
            }
        }
    }
    __syncthreads();

    /* phase 1: causal conv + bias + silu from LDS xz; outputs kept in regs */
    u16 vb[CLEN];
    {
        float w0 = cw[d*4], w1 = cw[d*4+1], w2 = cw[d*4+2], w3 = cw[d*4+3];
        float bias = cb[d];
        float xm3 = (l0 >= 3) ? bfu2f(smem[5 * XCP + d]) : 0.f;
        float xm2 = (l0 >= 2) ? bfu2f(smem[6 * XCP + d]) : 0.f;
        float xm1 = (l0 >= 1) ? bfu2f(smem[7 * XCP + d]) : 0.f;
        #pragma unroll
        for (int t = 0; t < CLEN; ++t) {
            float xcur = bfu2f(smem[(8 + t) * XCP + d]);
            float acc = fmaf(w0, xm3, fmaf(w1, xm2, fmaf(w2, xm1, fmaf(w3, xcur, bias))));
            vb[t] = f2bfu(siluf(acc));
            xcb[(size_t)(bl0 + t) * DI + d] = vb[t];
            xm3 = xm2; xm2 = xm1; xm1 = xcur;
        }
    }
    __syncthreads();               /* all xz reads done -> reuse smem */
    #pragma unroll
    for (int t = 0; t < CLEN; ++t) smem[t * XCP + d] = vb[t];   /* xc region */
    __syncthreads();

    /* phase 2: x_proj  xd[16,64] = xc[16,512] @ xpw[64,512]^T (K-split 8 waves) */
    {
        int wave = tid >> 6, lane = tid & 63;
        int row = lane & 15, q = lane >> 4;
        int nt = wave & 3, kh = wave >> 2;
        f32x4 acc = {0.f, 0.f, 0.f, 0.f};
        #pragma unroll
        for (int kb = 0; kb < 8; ++kb) {
            int kk = (kh*8 + kb) * 32;
            bf16x8 a = *(const bf16x8*)&smem[row * XCP + kk + q*8];
            bf16x8 bb = *(const bf16x8*)(xpw + (size_t)(nt*16 + row) * 512 + kk + q*8);
            acc = __builtin_amdgcn_mfma_f32_16x16x32_bf16(a, bb, acc, 0, 0, 0);
        }
        #pragma unroll
        for (int r = 0; r < 4; ++r)
            xd[kh * (CLEN*68) + (q*4 + r) * 68 + nt*16 + row] = acc[r];
    }
    __syncthreads();
    for (int j = tid; j < CLEN * 68; j += 512) xd[j] += xd[CLEN*68 + j];
    __syncthreads();

    /* store compact B,C (cols 16..47) for fused_c */
    {
        int t = tid >> 5, cc = tid & 31;
        BCg[(size_t)flat * (CLEN*32) + tid] = xd[t*68 + 16 + cc];
    }

    /* phase 3: dt = softplus(xd[:,:16] @ dtw^T + dtb); chunk scan -> P,S */
    {
        float dtwr[16];
        const f32x4* w4 = (const f32x4*)(dtw + (size_t)d * 16);
        #pragma unroll
        for (int g = 0; g < 4; ++g) { f32x4 v = w4[g];
            dtwr[g*4] = v[0]; dtwr[g*4+1] = v[1]; dtwr[g*4+2] = v[2]; dtwr[g*4+3] = v[3]; }
        float dtbv = dtb[d];
        float Ac0; bool fastp = true;
        {
            const f32x4* a4 = (const f32x4*)(Alog + (size_t)d * 16);
            f32x4 v0 = a4[0];
            Ac0 = -__expf(v0[0]);
            #pragma unroll
            for (int g = 0; g < 4; ++g) { f32x4 v = a4[g];
                #pragma unroll
                for (int j = 0; j < 4; ++j) { int n = g*4 + j; if (n) {
                    float acn = -__expf(v[j]);
                    fastp = fastp && (fabsf(acn - (float)(n+1)*Ac0) <= 1e-4f*fabsf(acn));
                } } }
        }
        float s[16];
        #pragma unroll
        for (int n = 0; n < 16; ++n) s[n] = 0.f;
        float Sdt = 0.f;
        if (fastp) {
            #pragma unroll
            for (int t = 0; t < CLEN; ++t) {
                float acc = dtbv;
                #pragma unroll
                for (int r = 0; r < 16; ++r) acc = fmaf(xd[t*68 + r], dtwr[r], acc);
                float dtraw = (acc > 20.0f) ? acc : logf(1.0f + __expf(acc));
                u16 dtu = f2bfu(dtraw);
                dtob[(size_t)(bl0 + t) * DI + d] = dtu;
                float dtv = bfu2f(dtu);
                float xv = bfu2f(vb[t]);
                float dx = dtv * xv;
                Sdt += dtv;
                float e1 = __expf(dtv * Ac0);
                float an[16];
                POW_TREE(an, e1)
                #pragma unroll
                for (int n = 0; n < 16; ++n)
                    s[n] = fmaf(an[n], s[n], xd[t*68 + 16 + n] * dx);
            }
        } else {
            #pragma unroll
            for (int t = 0; t < CLEN; ++t) {
                float acc = dtbv;
                #pragma unroll
                for (int r = 0; r < 16; ++r) acc = fmaf(xd[t*68 + r], dtwr[r], acc);
                float dtraw = (acc > 20.0f) ? acc : logf(1.0f + __expf(acc));
                u16 dtu = f2bfu(dtraw);
                dtob[(size_t)(bl0 + t) * DI + d] = dtu;
                float dtv = bfu2f(dtu);
                float xv = bfu2f(vb[t]);
                float dx = dtv * xv;
                Sdt += dtv;
                #pragma unroll
                for (int n = 0; n < 16; ++n) {
                    float an = __expf(dtv * -__expf(Alog[(size_t)d*16 + n]));
                    s[n] = fmaf(an, s[n], xd[t*68 + 16 + n] * dx);
                }
            }
        }
        float pw[16];
        if (fastp) {
            float E1 = __expf(Ac0 * Sdt);
            POW_TREE(pw, E1)
        } else {
            #pragma unroll
            for (int n = 0; n < 16; ++n)
                pw[n] = __expf(-__expf(Alog[(size_t)d*16 + n]) * Sdt);
        }
        size_t base = ((size_t)flat * DI + d) * 16;
        u16x8 pv0, pv1, sv0, sv1;
        #pragma unroll
        for (int n = 0; n < 8; ++n) {
            pv0[n] = f2bfu(pw[n]);  pv1[n] = f2bfu(pw[8+n]);
            sv0[n] = f2bfu(s[n]);   sv1[n] = f2bfu(s[8+n]);
        }
        *(u16x8*)(Pb + base)     = pv0;  *(u16x8*)(Pb + base + 8) = pv1;
        *(u16x8*)(Sb + base)     = sv0;  *(u16x8*)(Sb + base + 8) = sv1;
    }
}

/* ---------------- scan12: merged superchunk scan + entry states -------------- */
/* block = 1024 thr = 16 sc x 64 elow; aggregates exchanged via LDS;
   P/S kept in regs for replay.  grid (8192/64, BATCH). */
__global__ __launch_bounds__(1024) void scan12_k(
    const u16* __restrict__ Pb, const u16* __restrict__ Sb,
    u16* __restrict__ Hg) {
    __shared__ float pag[NSC][64], sag[NSC][64];
    int tid = threadIdx.x;
    int eo = tid & 63, sc = tid >> 6;
    int elow = blockIdx.x * 64 + eo;
    int b = blockIdx.y;
    int cbase = b * NCH + sc * 16;
    float Pr[16], Sr[16];
    float h = 0.f, p = 1.f;
    #pragma unroll
    for (int k = 0; k < 16; ++k) {
        size_t a = (size_t)(cbase + k) * 8192 + elow;
        Pr[k] = bfu2f(Pb[a]); Sr[k] = bfu2f(Sb[a]);
        h = fmaf(Pr[k], h, Sr[k]);
        p *= Pr[k];
    }
    pag[sc][eo] = p; sag[sc][eo] = h;
    __syncthreads();
    float hs = 0.f;
    for (int s2 = 0; s2 < sc; ++s2)            /* sc uniform per wave */
        hs = fmaf(pag[s2][eo], hs, sag[s2][eo]);
    #pragma unroll
    for (int k = 0; k < 16; ++k) {
        size_t a = (size_t)(cbase + k) * 8192 + elow;
        Hg[a] = f2bfu(hs);
        hs = fmaf(Pr[k], hs, Sr[k]);
    }
}

/* ---------------- fused C: scan replay -> y slab (LDS) -> out_proj MFMA ------- */
__global__ __launch_bounds__(512, 6) void fused_c_k(
    const u16* __restrict__ xcb, const u16* __restrict__ dtob,
    const float* __restrict__ BCg, const u16* __restrict__ Hg,
    const float* __restrict__ Alog, const float* __restrict__ Dp,
    const u16* __restrict__ gate, const __bf16* __restrict__ outw,
    u16* __restrict__ Ob, float* __restrict__ Of) {
    __shared__ u16 y_s[CLEN * XCP];        /* 16.6 KB */
    __shared__ float BCs[CLEN * 32];       /* 2 KB */
    int tid = threadIdx.x;
    int c = blockIdx.x, b = blockIdx.y;
    int flat = b * NCH + c;
    int bl0 = b * LSEQ + c * CLEN;
    int d = tid;

    BCs[tid] = BCg[(size_t)flat * (CLEN*32) + tid];

    float Ac0; bool fastp = true;
    {
        const f32x4* a4 = (const f32x4*)(Alog + (size_t)d * 16);
        f32x4 v0 = a4[0];
        Ac0 = -__expf(v0[0]);
        #pragma unroll
        for (int g = 0; g < 4; ++g) { f32x4 v = a4[g];
            #pragma unroll
            for (int j = 0; j < 4; ++j) { int n = g*4 + j; if (n) {
                float acn = -__expf(v[j]);
                fastp = fastp && (fabsf(acn - (float)(n+1)*Ac0) <= 1e-4f*fabsf(acn));
            } } }
    }
    float h[16];
    {
        const u16* h8 = Hg + ((size_t)flat * DI + d) * 16;
        u16x8 hv0 = *(const u16x8*)h8;
        u16x8 hv1 = *(const u16x8*)(h8 + 8);
        #pragma unroll
        for (int n = 0; n < 8; ++n) { h[n] = bfu2f(hv0[n]); h[8+n] = bfu2f(hv1[n]); }
    }
    float Dv = Dp[d];
    __syncthreads();

    if (fastp) {
        for (int t = 0; t < CLEN; ++t) {
            float dtv = bfu2f(dtob[(size_t)(bl0 + t) * DI + d]);
            float xv  = bfu2f(xcb[(size_t)(bl0 + t) * DI + d]);
            float gv  = bfu2f(gate[(size_t)(bl0 + t) * 512 + d]);
            float dx = dtv * xv;
            float e1 = __expf(dtv * Ac0);
            float an[16];
            POW_TREE(an, e1)
            float y0 = 0.f, y1 = 0.f, y2 = 0.f, y3 = 0.f;
            #pragma unroll
            for (int n = 0; n < 4; ++n) {
                h[n]    = fmaf(an[n],    h[n],    BCs[t*32 + n]    * dx);
                h[4+n]  = fmaf(an[4+n],  h[4+n],  BCs[t*32 + 4+n]  * dx);
                h[8+n]  = fmaf(an[8+n],  h[8+n],  BCs[t*32 + 8+n]  * dx);
                h[12+n] = fmaf(an[12+n], h[12+n], BCs[t*32 + 12+n] * dx);
                y0 = fmaf(h[n],    BCs[t*32 + 16 + n],    y0);
                y1 = fmaf(h[4+n],  BCs[t*32 + 16 + 4+n],  y1);
                y2 = fmaf(h[8+n],  BCs[t*32 + 16 + 8+n],  y2);
                y3 = fmaf(h[12+n], BCs[t*32 + 16 + 12+n], y3);
            }
            float y = (y0 + y1) + (y2 + y3);
            float yv = fmaf(xv, Dv, y) * siluf(gv);
            y_s[t * XCP + d] = f2bfu(yv);
        }
    } else {
        for (int t = 0; t < CLEN; ++t) {
            float dtv = bfu2f(dtob[(size_t)(bl0 + t) * DI + d]);
            float xv  = bfu2f(xcb[(size_t)(bl0 + t) * DI + d]);
            float gv  = bfu2f(gate[(size_t)(bl0 + t) * 512 + d]);
            float dx = dtv * xv;
            float y = 0.f;
            #pragma unroll
            for (int n = 0; n < 16; ++n) {
                float an = __expf(dtv * -__expf(Alog[(size_t)d*16 + n]));
                h[n] = fmaf(an, h[n], BCs[t*32 + n] * dx);
                y = fmaf(h[n], BCs[t*32 + 16 + n], y);
            }
            float yv = fmaf(xv, Dv, y) * siluf(gv);
            y_s[t * XCP + d] = f2bfu(yv);
        }
    }
    __syncthreads();

    /* out_proj: O[16,256] = y_s[16,512] @ outw[256,512]^T; 8 waves x 2 N-tiles */
    {
        int wave = tid >> 6, lane = tid & 63;
        int row = lane & 15, q = lane >> 4;
        f32x4 acc[2] = {};
        #pragma unroll
        for (int kb = 0; kb < 16; ++kb) {
            bf16x8 a = *(const bf16x8*)&y_s[row * XCP + kb*32 + q*8];
            #pragma unroll
            for (int ni = 0; ni < 2; ++ni) {
                bf16x8 bb = *(const bf16x8*)(outw +
                    (size_t)(wave*32 + ni*16 + row) * 512 + kb*32 + q*8);
                acc[ni] = __builtin_amdgcn_mfma_f32_16x16x32_bf16(a, bb, acc[ni], 0, 0, 0);
            }
        }
        #pragma unroll
        for (int r = 0; r < 4; ++r) {
            size_t gr = (size_t)(bl0 + q*4 + r) * DM;
            #pragma unroll
            for (int ni = 0; ni < 2; ++ni) {
                int gc = wave*32 + ni*16 + row;
                if (Ob) Ob[gr + gc] = f2bfu(acc[ni][r]);
                else    Of[gr + gc] = acc[ni][r];
            }
        }
    }
}

/* ================================================================== */
extern "C" void kernel_launch(void* const* d_in, const int* in_sizes, int n_in,
                              void* d_out, int out_size, void* d_ws, size_t ws_size,
                              hipStream_t stream) {
    (void)in_sizes; (void)n_in; (void)out_size; (void)ws_size;
    const float* z_in   = (const float*)d_in[0];
    const float* in_w   = (const float*)d_in[1];
    const float* conv_w = (const float*)d_in[2];
    const float* conv_b = (const float*)d_in[3];
    const float* xp_w   = (const float*)d_in[4];
    const float* dt_w   = (const float*)d_in[5];
    const float* dt_b   = (const float*)d_in[6];
    const float* A_log  = (const float*)d_in[7];
    const float* D_par  = (const float*)d_in[8];
    const float* out_w  = (const float*)d_in[9];
    float* outp = (float*)d_out;

    char* p = (char*)d_ws;
    auto alloc = [&](size_t bytes) { char* r = p; p += (bytes + 255) & ~(size_t)255; return r; };
    u16* z_bf    = (u16*)alloc((size_t)BLROWS*DM*2);
    u16* z2_bf   = (u16*)alloc((size_t)BLROWS*DM*2);
    u16* gate_bf = (u16*)alloc((size_t)BLROWS*DI*2);
    u16* xc_bf   = (u16*)alloc((size_t)BLROWS*DI*2);
    u16* dt_bf   = (u16*)alloc((size_t)BLROWS*DI*2);
    u16* inw_bf  = (u16*)alloc((size_t)2*1024*256*2);
    u16* outw_bf = (u16*)alloc((size_t)2*256*512*2);
    u16* xpw_bf  = (u16*)alloc((size_t)2*64*512*2);
    float* BCg   = (float*)alloc((size_t)BATCH*NCH*CLEN*32*4);
    u16* Pbuf    = (u16*)alloc((size_t)BATCH*NCH*DI*DS*2);
    u16* Sbuf    = (u16*)alloc((size_t)BATCH*NCH*DI*DS*2);
    u16* Hbuf    = (u16*)alloc((size_t)BATCH*NCH*DI*DS*2);

    cast_all_k<<<(N_INW + N_OUTW + N_XPW + N_Z)/256, 256, 0, stream>>>(
        in_w, out_w, xp_w, z_in, inw_bf, outw_bf, xpw_bf, z_bf);

    const u16* zcur = z_bf;
    for (int l = 0; l < 2; ++l) {
        fused_a_k<<<dim3(NCH, BATCH), 512, 0, stream>>>(
            (const __bf16*)zcur, (const __bf16*)(inw_bf + (size_t)l*1024*256),
            conv_w + (size_t)l*DI*4, conv_b + (size_t)l*DI,
            (const __bf16*)(xpw_bf + (size_t)l*64*512),
            dt_w + (size_t)l*DI*16, dt_b + (size_t)l*DI,
            A_log + (size_t)l*DI*DS,
            gate_bf, xc_bf, dt_bf, BCg, Pbuf, Sbuf);
        scan12_k<<<dim3(8192/64, BATCH), 1024, 0, stream>>>(Pbuf, Sbuf, Hbuf);
        fused_c_k<<<dim3(NCH, BATCH), 512, 0, stream>>>(
            xc_bf, dt_bf, BCg, Hbuf,
            A_log + (size_t)l*DI*DS, D_par + (size_t)l*DI,
            gate_bf, (const __bf16*)(outw_bf + (size_t)l*256*512),
            (l == 0) ? z2_bf : nullptr, (l == 1) ? outp : nullptr);
        zcur = z2_bf;
    }
}